// Round 6
// baseline (1271.147 us; speedup 1.0000x reference)
//
#include <hip/hip_runtime.h>
#include <math.h>

// ---- problem constants ----
#define K_NB 20
#define DIM  128     // D
#define TDIM 128     // TD
#define IMP  100
#define DKQ  256     // DK
#define HID  1024    // H
#define FEAT 484
#define FB   384     // base feature cols (nx|ex|etx)
#define NB1  5120    // B*K rows at depth 1
#define NB2  256     // B rows at depth 2
#define FROW 488     // featb row stride in attn LDS

__device__ __forceinline__ float sigmoidf_(float x) { return 1.f / (1.f + expf(-x)); }

// ---------------------------------------------------------------------------
// P1: VW = [Wv[0:384] ; W2@Wv[384:484]], WK = [Wk[0:384] ; W2@Wk[384:484]],
//     qc0 = cos(time_b)@Wq[128:256],  cv0 = b2@Wv[384:484]
// ---------------------------------------------------------------------------
__global__ __launch_bounds__(256) void precompute_k(
    const float* __restrict__ time_b, const float* __restrict__ imp_b2,
    const float* __restrict__ Wq, const float* __restrict__ Wk,
    const float* __restrict__ Wv, const float* __restrict__ W2,
    float* __restrict__ VW, float* __restrict__ WK,
    float* __restrict__ qc0, float* __restrict__ cv0)
{
    int b = blockIdx.x, t = threadIdx.x;
    if (b < FB) {
        VW[b * DKQ + t] = Wv[b * DKQ + t];
        WK[b * DKQ + t] = Wk[b * DKQ + t];
    } else if (b < FB + IMP) {
        int j = b - FB; float aV = 0.f, aK = 0.f;
        for (int m = 0; m < IMP; m++) {
            float w = W2[j * IMP + m];
            aV += w * Wv[(FB + m) * DKQ + t];
            aK += w * Wk[(FB + m) * DKQ + t];
        }
        VW[b * DKQ + t] = aV;
        WK[b * DKQ + t] = aK;
    } else if (b == FB + IMP) {
        float acc = 0.f;
        for (int j = 0; j < TDIM; j++) acc += cosf(time_b[j]) * Wq[(DIM + j) * DKQ + t];
        qc0[t] = acc;
    } else {
        float acc = 0.f;
        for (int m = 0; m < IMP; m++) acc += imp_b2[m] * Wv[(FB + m) * DKQ + t];
        cv0[t] = acc;
    }
}

// ---------------------------------------------------------------------------
// P2: WQK[d][n] = (1/16)·dot(Wq[d][:], WK[n][:])   (128 x 484)
//     kc0[n]    = (1/16)·dot(qc0,      WK[n][:])
// Folds the entire Q projection: KQ = CX @ WQK + kc0.
// ---------------------------------------------------------------------------
__global__ __launch_bounds__(128) void precompute2_k(
    const float* __restrict__ Wq, const float* __restrict__ WK,
    const float* __restrict__ qc0, float* __restrict__ WQK, float* __restrict__ kc0)
{
    const int n = blockIdx.x, d = threadIdx.x;
    float acc = 0.f;
    for (int t = 0; t < DKQ; t++) acc += Wq[d * DKQ + t] * WK[n * DKQ + t];
    WQK[d * FEAT + n] = acc * 0.0625f;
    if (d == 0) {
        float a2 = 0.f;
        for (int t = 0; t < DKQ; t++) a2 += qc0[t] * WK[n * DKQ + t];
        kc0[n] = a2 * 0.0625f;
    }
}

// ---------------------------------------------------------------------------
// CX[i][c] = node_reprs[cid][c] + node_embed[cid][c]; float4, 4 rows/block
// ---------------------------------------------------------------------------
__global__ __launch_bounds__(128) void cx_gather_k(
    const float* __restrict__ nr, const float* __restrict__ ne,
    const int* __restrict__ cids, float* __restrict__ CX, int nrows)
{
    int r = blockIdx.x * 4 + (threadIdx.x >> 5);
    if (r >= nrows) return;
    int c4 = (threadIdx.x & 31);
    int nid = cids[r];
    const float4 a = ((const float4*)(nr + (size_t)nid * DIM))[c4];
    const float4 b = ((const float4*)(ne + (size_t)nid * DIM))[c4];
    float4 o; o.x = a.x + b.x; o.y = a.y + b.y; o.z = a.z + b.z; o.w = a.w + b.w;
    ((float4*)(CX + (size_t)r * DIM))[c4] = o;
}

// ---------------------------------------------------------------------------
// Tiled f32 GEMM: C[M,N] = (A|A2 at asplit)[M,K] @ B (+bias)*scale
// Template BM x BN tile, 8x4 micro-tile, NT = (BM/8)*(BN/4) threads.
// BT=false: B[K,N] row-major; BT=true: B[N,K] row-major (C = A@B^T).
// Requires BM | M. N, K arbitrary (guarded).
// ---------------------------------------------------------------------------
template <int BM, int BN, bool BT>
__global__ __launch_bounds__((BM / 8) * (BN / 4)) void gemm_f32(
    const float* __restrict__ A, const float* __restrict__ A2, int asplit, int lda2,
    const float* __restrict__ B, const float* __restrict__ bias,
    float* __restrict__ C, int M, int N, int K, int lda, int ldb, int ldc, float scale)
{
    constexpr int NT = (BM / 8) * (BN / 4);
    constexpr int EA = BM * 16 / NT;
    constexpr int EB = BN * 16 / NT;
    constexpr int TROW = BN / 4;
    __shared__ float As[16][BM + 4];
    __shared__ float Bs[16][BN + 4];
    const int tid = threadIdx.x;
    const int bm = blockIdx.y * BM, bn = blockIdx.x * BN;
    const int tm = (tid / TROW) * 8, tn = (tid % TROW) * 4;
    float acc[8][4] = {};

    for (int k0 = 0; k0 < K; k0 += 16) {
#pragma unroll
        for (int i = 0; i < EA; i++) {       // A tile: BM rows x 16 k
            int flat = tid * EA + i;
            int r = flat >> 4, kc = flat & 15;
            int gk = k0 + kc;
            float v = 0.f;
            if (gk < K) {
                int gr = bm + r;
                v = (A2 && gk >= asplit) ? A2[(size_t)gr * lda2 + (gk - asplit)]
                                         : A[(size_t)gr * lda + gk];
            }
            As[kc][r] = v;
        }
        if (!BT) {                            // B[k][n] -> Bs[k][n]
#pragma unroll
            for (int i = 0; i < EB; i++) {
                int flat = tid * EB + i;
                int kb = flat / BN, nb = flat % BN;
                int gk = k0 + kb, gn = bn + nb;
                Bs[kb][nb] = (gk < K && gn < N) ? B[(size_t)gk * ldb + gn] : 0.f;
            }
        } else {                              // B[n][k] -> Bs[k][n]
#pragma unroll
            for (int i = 0; i < EB; i++) {
                int flat = tid * EB + i;
                int n = flat >> 4, kc = flat & 15;
                int gn = bn + n, gk = k0 + kc;
                Bs[kc][n] = (gn < N && gk < K) ? B[(size_t)gn * ldb + gk] : 0.f;
            }
        }
        __syncthreads();
#pragma unroll
        for (int kk = 0; kk < 16; kk++) {
            float a[8], b[4];
#pragma unroll
            for (int i = 0; i < 8; i++) a[i] = As[kk][tm + i];
#pragma unroll
            for (int j = 0; j < 4; j++) b[j] = Bs[kk][tn + j];
#pragma unroll
            for (int i = 0; i < 8; i++)
#pragma unroll
                for (int j = 0; j < 4; j++) acc[i][j] += a[i] * b[j];
        }
        __syncthreads();
    }
#pragma unroll
    for (int i = 0; i < 8; i++) {
        int gm = bm + tm + i;
#pragma unroll
        for (int j = 0; j < 4; j++) {
            int gn = bn + tn + j;
            if (gn >= N) continue;
            float v = acc[i][j];
            if (bias) v += bias[gn];
            C[(size_t)gm * ldc + gn] = v * scale;
        }
    }
}

// ---------------------------------------------------------------------------
// attn_rows_k: 8 half-wave groups gather neighbors with fused score dot;
// wave-parallel softmax; float4 weighted-sum epilogue.
// ---------------------------------------------------------------------------
template <int DEPTH>
__global__ __launch_bounds__(256) void attn_rows_k(
    const float* __restrict__ nr, const float* __restrict__ ne,
    const float* __restrict__ ee, const float* __restrict__ h1,
    const int* __restrict__ nids, const int* __restrict__ eids,
    const float* __restrict__ nts, const float* __restrict__ deg,
    const float* __restrict__ re, const float* __restrict__ ts,
    const float* __restrict__ tw, const float* __restrict__ tb,
    const float* __restrict__ iw1, const float* __restrict__ ib1,
    const float* __restrict__ KQ, float* __restrict__ WFB)
{
    __shared__ float featb[K_NB][FROW];
    __shared__ float kq_s[FROW];
    __shared__ float score[K_NB], attn_l[K_NB];
    __shared__ float dt_s[K_NB], ss_s[K_NB];
    __shared__ int nid_s[K_NB], eid_s[K_NB];

    const int row = blockIdx.x, tid = threadIdx.x;
    const int g = tid >> 5, l = tid & 31;

    if (tid < K_NB) {
        int nid = nids[row * K_NB + tid];
        nid_s[tid] = nid; eid_s[tid] = eids[row * K_NB + tid];
        float tc = (DEPTH == 1) ? ts[row / K_NB] : ts[row];
        dt_s[tid] = tc - nts[row * K_NB + tid];
        float rv = re[row * K_NB + tid];
        ss_s[tid] = (rv == 0.f) ? 0.f : deg[row * K_NB + tid] / rv;
    }
    kq_s[tid] = KQ[(size_t)row * FEAT + tid];
    if (tid < FEAT - 256) kq_s[256 + tid] = KQ[(size_t)row * FEAT + 256 + tid];
    __syncthreads();

    for (int rr = g; rr < K_NB; rr += 8) {
        const int nid = nid_s[rr], eid = eid_s[rr];
        float4 xa;
        if (DEPTH == 1) {
            const float4 a = ((const float4*)(nr + (size_t)nid * DIM))[l];
            const float4 b = ((const float4*)(ne + (size_t)nid * DIM))[l];
            xa.x = a.x + b.x; xa.y = a.y + b.y; xa.z = a.z + b.z; xa.w = a.w + b.w;
        } else {
            xa = ((const float4*)(h1 + ((size_t)row * K_NB + rr) * DIM))[l];
        }
        const float4 xe = ((const float4*)(ee + (size_t)eid * DIM))[l];
        const float dt = dt_s[rr];
        const float4 tw4 = ((const float4*)tw)[l];
        const float4 tb4 = ((const float4*)tb)[l];
        float4 xt;
        xt.x = __cosf(dt * tw4.x + tb4.x);
        xt.y = __cosf(dt * tw4.y + tb4.y);
        xt.z = __cosf(dt * tw4.z + tb4.z);
        xt.w = __cosf(dt * tw4.w + tb4.w);

        ((float4*)&featb[rr][0])[l]   = xa;
        ((float4*)&featb[rr][128])[l] = xe;
        ((float4*)&featb[rr][256])[l] = xt;

        const int c = 4 * l;
        float sc = xa.x * kq_s[c]       + xa.y * kq_s[c + 1]       + xa.z * kq_s[c + 2]       + xa.w * kq_s[c + 3]
                 + xe.x * kq_s[128 + c] + xe.y * kq_s[128 + c + 1] + xe.z * kq_s[128 + c + 2] + xe.w * kq_s[128 + c + 3]
                 + xt.x * kq_s[256 + c] + xt.y * kq_s[256 + c + 1] + xt.z * kq_s[256 + c + 2] + xt.w * kq_s[256 + c + 3];
        if (l < IMP / 4) {
            const float s = ss_s[rr];
            const float4 w1 = ((const float4*)iw1)[l];
            const float4 b1 = ((const float4*)ib1)[l];
            float4 hv;
            hv.x = fmaxf(s * w1.x + b1.x, 0.f);
            hv.y = fmaxf(s * w1.y + b1.y, 0.f);
            hv.z = fmaxf(s * w1.z + b1.z, 0.f);
            hv.w = fmaxf(s * w1.w + b1.w, 0.f);
            ((float4*)&featb[rr][FB])[l] = hv;
            sc += hv.x * kq_s[FB + c] + hv.y * kq_s[FB + c + 1]
                + hv.z * kq_s[FB + c + 2] + hv.w * kq_s[FB + c + 3];
        }
#pragma unroll
        for (int off = 16; off >= 1; off >>= 1) sc += __shfl_down(sc, off, 32);
        if (l == 0) score[rr] = sc;
    }
    __syncthreads();

    if (tid < 32) {
        float sc = (tid < K_NB) ? ((nid_s[tid] == 0) ? -1e9f : score[tid]) : -3.0e38f;
        float mx = sc;
#pragma unroll
        for (int off = 16; off >= 1; off >>= 1) mx = fmaxf(mx, __shfl_xor(mx, off, 32));
        float e = __expf(sc - mx);
        float sum = e;
#pragma unroll
        for (int off = 16; off >= 1; off >>= 1) sum += __shfl_xor(sum, off, 32);
        if (tid < K_NB) attn_l[tid] = e / sum;
    }
    __syncthreads();

    if (tid < FEAT / 4) {
        float4 acc = {0.f, 0.f, 0.f, 0.f};
#pragma unroll 4
        for (int r = 0; r < K_NB; r++) {
            const float a = attn_l[r];
            const float4 f = ((const float4*)&featb[r][0])[tid];
            acc.x += a * f.x; acc.y += a * f.y; acc.z += a * f.z; acc.w += a * f.w;
        }
        ((float4*)(WFB + (size_t)row * FEAT))[tid] = acc;
    }
}

// ---------------------------------------------------------------------------
// HN = lstm(CTX @ wih[:, {i,g,o}] + b):  h = sig(o)*tanh(sig(i)*tanh(g))
// BM=64, BN=64 (of 1024), K=256. f-gate skipped (c_old = 0).
// ---------------------------------------------------------------------------
__global__ __launch_bounds__(256) void gates_hn_k(
    const float* __restrict__ CTX, const float* __restrict__ wih,
    const float* __restrict__ bias, float* __restrict__ HN, int M)
{
    __shared__ float As[16][68];
    __shared__ float Bs[3][16][68];
    const int tid = threadIdx.x;
    const int bm = blockIdx.y * 64, bn = blockIdx.x * 64;
    const int tm = (tid >> 4) * 4, tn = (tid & 15) * 4;
    float acc[3][4][4] = {};
    const int goff0 = 0, goff1 = 2048, goff2 = 3072;

    for (int k0 = 0; k0 < DKQ; k0 += 16) {
        int r = tid >> 2, kc = (tid & 3) * 4;
#pragma unroll
        for (int i = 0; i < 4; i++) As[kc + i][r] = CTX[(bm + r) * DKQ + k0 + kc + i];
        int kb = tid >> 4, nb = (tid & 15) * 4;
#pragma unroll
        for (int i = 0; i < 4; i++) {
            Bs[0][kb][nb + i] = wih[(k0 + kb) * 4096 + goff0 + bn + nb + i];
            Bs[1][kb][nb + i] = wih[(k0 + kb) * 4096 + goff1 + bn + nb + i];
            Bs[2][kb][nb + i] = wih[(k0 + kb) * 4096 + goff2 + bn + nb + i];
        }
        __syncthreads();
#pragma unroll
        for (int kk = 0; kk < 16; kk++) {
            float a[4], b0[4], b1[4], b2v[4];
#pragma unroll
            for (int i = 0; i < 4; i++) a[i] = As[kk][tm + i];
#pragma unroll
            for (int j = 0; j < 4; j++) {
                b0[j] = Bs[0][kk][tn + j]; b1[j] = Bs[1][kk][tn + j]; b2v[j] = Bs[2][kk][tn + j];
            }
#pragma unroll
            for (int i = 0; i < 4; i++)
#pragma unroll
                for (int j = 0; j < 4; j++) {
                    acc[0][i][j] += a[i] * b0[j];
                    acc[1][i][j] += a[i] * b1[j];
                    acc[2][i][j] += a[i] * b2v[j];
                }
        }
        __syncthreads();
    }
#pragma unroll
    for (int i = 0; i < 4; i++)
#pragma unroll
        for (int j = 0; j < 4; j++) {
            int n = bn + tn + j;
            float iv = acc[0][i][j] + bias[n];
            float gv = acc[1][i][j] + bias[2048 + n];
            float ov = acc[2][i][j] + bias[3072 + n];
            float c = sigmoidf_(iv) * tanhf(gv);
            HN[(bm + tm + i) * HID + n] = sigmoidf_(ov) * tanhf(c);
        }
}

// ---------------------------------------------------------------------------
extern "C" void kernel_launch(void* const* d_in, const int* in_sizes, int n_in,
                              void* d_out, int out_size, void* d_ws, size_t ws_size,
                              hipStream_t stream)
{
    const float* nr   = (const float*)d_in[0];
    const float* ne   = (const float*)d_in[1];
    const float* ee   = (const float*)d_in[2];
    const float* tw   = (const float*)d_in[3];
    const float* tb   = (const float*)d_in[4];
    const float* iw1  = (const float*)d_in[5];
    const float* ib1  = (const float*)d_in[6];
    const float* W2   = (const float*)d_in[7];
    const float* ib2  = (const float*)d_in[8];
    const float* Wq   = (const float*)d_in[9];
    const float* Wk   = (const float*)d_in[10];
    const float* Wv   = (const float*)d_in[11];
    const float* wih  = (const float*)d_in[12];
    /* lstm_whh d_in[13] unused: h0 == 0 */
    const float* lb   = (const float*)d_in[14];
    const float* Wout = (const float*)d_in[15];
    const float* ts     = (const float*)d_in[16];
    const float* n2_ts  = (const float*)d_in[17];
    const float* n1_ts  = (const float*)d_in[18];
    const float* n2_re  = (const float*)d_in[19];
    const float* n2_deg = (const float*)d_in[20];
    const float* n1_re  = (const float*)d_in[21];
    const float* n1_deg = (const float*)d_in[22];
    const int* center_nids = (const int*)d_in[23];
    const int* n2_nids     = (const int*)d_in[24];
    const int* n2_eids     = (const int*)d_in[25];
    const int* n1_nids     = (const int*)d_in[26];
    const int* n1_eids     = (const int*)d_in[27];

    // ---- workspace layout (~33 MB peak; HN aliases dead KQ|WFB|tail) ----
    float* ws   = (float*)d_ws;
    float* VW   = ws;                        // 484*256 = 123904
    float* WK   = VW  + FEAT * DKQ;          // 123904
    float* qc0  = WK  + FEAT * DKQ;          // 256
    float* cv0  = qc0 + DKQ;                 // 256
    float* WQK  = cv0 + DKQ;                 // 128*484 = 61952
    float* kc0  = WQK + DIM * FEAT;          // 512
    float* CX   = kc0 + 512;                 // 5120*128
    float* H1   = CX  + NB1 * DIM;           // 5120*128
    float* CTX  = H1  + NB1 * DIM;           // 5120*256
    float* KQ   = CTX + NB1 * DKQ;           // 5120*484
    float* WFB  = KQ  + NB1 * FEAT;          // 5120*484
    float* HN   = KQ;                        // 5120*1024 = 5242880 over KQ|WFB|tail
    // region from KQ: 2*2478080 + tail = 5242880 needed; peak 32.7 MB < R3's proven 36.5 MB

    precompute_k<<<FB + IMP + 2, 256, 0, stream>>>(tb, ib2, Wq, Wk, Wv, W2, VW, WK, qc0, cv0);
    precompute2_k<<<FEAT, 128, 0, stream>>>(Wq, WK, qc0, WQK, kc0);

    // ================= depth 1 (M = 5120) =================
    {
        const int M = NB1;
        cx_gather_k<<<M / 4, 128, 0, stream>>>(nr, ne, n2_nids, CX, M);
        gemm_f32<64, 64, false><<<dim3(8, M / 64), 128, 0, stream>>>(
            CX, nullptr, 0, 0, WQK, kc0, KQ, M, FEAT, DIM, DIM, FEAT, FEAT, 1.f);
        attn_rows_k<1><<<M, 256, 0, stream>>>(nr, ne, ee, nullptr,
            n1_nids, n1_eids, n1_ts, n1_deg, n1_re, ts, tw, tb, iw1, ib1, KQ, WFB);
        gemm_f32<64, 64, false><<<dim3(4, M / 64), 128, 0, stream>>>(
            WFB, nullptr, 0, 0, VW, cv0, CTX, M, DKQ, FEAT, FEAT, DKQ, DKQ, 1.f);
        gates_hn_k<<<dim3(16, M / 64), 256, 0, stream>>>(CTX, wih, lb, HN, M);
        gemm_f32<64, 32, false><<<dim3(4, M / 64), 64, 0, stream>>>(
            CX, HN, DIM, HID, Wout, nullptr, H1, M, DIM, DIM + HID, DIM, DIM, DIM, 1.f);
    }
    // ================= depth 2 (M = 256) =================
    {
        const int M = NB2;
        cx_gather_k<<<M / 4, 128, 0, stream>>>(nr, ne, center_nids, CX, M);
        gemm_f32<64, 64, false><<<dim3(8, M / 64), 128, 0, stream>>>(
            CX, nullptr, 0, 0, WQK, kc0, KQ, M, FEAT, DIM, DIM, FEAT, FEAT, 1.f);
        attn_rows_k<2><<<M, 256, 0, stream>>>(nr, ne, ee, H1,
            n2_nids, n2_eids, n2_ts, n2_deg, n2_re, ts, tw, tb, iw1, ib1, KQ, WFB);
        gemm_f32<64, 64, false><<<dim3(4, M / 64), 128, 0, stream>>>(
            WFB, nullptr, 0, 0, VW, cv0, CTX, M, DKQ, FEAT, FEAT, DKQ, DKQ, 1.f);
        gates_hn_k<<<dim3(16, M / 64), 256, 0, stream>>>(CTX, wih, lb, HN, M);
        gemm_f32<64, 32, false><<<dim3(4, M / 64), 64, 0, stream>>>(
            CX, HN, DIM, HID, Wout, nullptr, (float*)d_out, M, DIM, DIM + HID, DIM, DIM, DIM, 1.f);
    }
}

// Round 7
// 878.024 us; speedup vs baseline: 1.4477x; 1.4477x over previous
//
#include <hip/hip_runtime.h>
#include <math.h>

// ---- problem constants ----
#define K_NB 20
#define DIM  128     // D
#define TDIM 128     // TD
#define IMP  100
#define DKQ  256     // DK
#define HID  1024    // H
#define FEAT 484
#define FB   384     // base feature cols (nx|ex|etx)
#define NB1  5120    // B*K rows at depth 1
#define NB2  256     // B rows at depth 2
#define FROW 488     // featb row stride in attn LDS

__device__ __forceinline__ float sigmoidf_(float x) { return 1.f / (1.f + expf(-x)); }

// ---------------------------------------------------------------------------
// P1: VW = [Wv[0:384] ; W2@Wv[384:484]], WK = [Wk[0:384] ; W2@Wk[384:484]],
//     qc0 = cos(time_b)@Wq[128:256],  cv0 = b2@Wv[384:484]
// ---------------------------------------------------------------------------
__global__ __launch_bounds__(256) void precompute_k(
    const float* __restrict__ time_b, const float* __restrict__ imp_b2,
    const float* __restrict__ Wq, const float* __restrict__ Wk,
    const float* __restrict__ Wv, const float* __restrict__ W2,
    float* __restrict__ VW, float* __restrict__ WK,
    float* __restrict__ qc0, float* __restrict__ cv0)
{
    int b = blockIdx.x, t = threadIdx.x;
    if (b < FB) {
        VW[b * DKQ + t] = Wv[b * DKQ + t];
        WK[b * DKQ + t] = Wk[b * DKQ + t];
    } else if (b < FB + IMP) {
        int j = b - FB; float aV = 0.f, aK = 0.f;
        for (int m = 0; m < IMP; m++) {
            float w = W2[j * IMP + m];
            aV += w * Wv[(FB + m) * DKQ + t];
            aK += w * Wk[(FB + m) * DKQ + t];
        }
        VW[b * DKQ + t] = aV;
        WK[b * DKQ + t] = aK;
    } else if (b == FB + IMP) {
        float acc = 0.f;
        for (int j = 0; j < TDIM; j++) acc += cosf(time_b[j]) * Wq[(DIM + j) * DKQ + t];
        qc0[t] = acc;
    } else {
        float acc = 0.f;
        for (int m = 0; m < IMP; m++) acc += imp_b2[m] * Wv[(FB + m) * DKQ + t];
        cv0[t] = acc;
    }
}

// ---------------------------------------------------------------------------
// P2: WQK[d][n] = (1/16)·dot(Wq[d][:], WK[n][:])   (128 x 484)
//     kc0[n]    = (1/16)·dot(qc0,      WK[n][:])
// ---------------------------------------------------------------------------
__global__ __launch_bounds__(128) void precompute2_k(
    const float* __restrict__ Wq, const float* __restrict__ WK,
    const float* __restrict__ qc0, float* __restrict__ WQK, float* __restrict__ kc0)
{
    const int n = blockIdx.x, d = threadIdx.x;
    float acc = 0.f;
    for (int t = 0; t < DKQ; t++) acc += Wq[d * DKQ + t] * WK[n * DKQ + t];
    WQK[d * FEAT + n] = acc * 0.0625f;
    if (d == 0) {
        float a2 = 0.f;
        for (int t = 0; t < DKQ; t++) a2 += qc0[t] * WK[n * DKQ + t];
        kc0[n] = a2 * 0.0625f;
    }
}

// ---------------------------------------------------------------------------
// CX[i][c] = node_reprs[cid][c] + node_embed[cid][c]; float4, 4 rows/block
// ---------------------------------------------------------------------------
__global__ __launch_bounds__(128) void cx_gather_k(
    const float* __restrict__ nr, const float* __restrict__ ne,
    const int* __restrict__ cids, float* __restrict__ CX, int nrows)
{
    int r = blockIdx.x * 4 + (threadIdx.x >> 5);
    if (r >= nrows) return;
    int c4 = (threadIdx.x & 31);
    int nid = cids[r];
    const float4 a = ((const float4*)(nr + (size_t)nid * DIM))[c4];
    const float4 b = ((const float4*)(ne + (size_t)nid * DIM))[c4];
    float4 o; o.x = a.x + b.x; o.y = a.y + b.y; o.z = a.z + b.z; o.w = a.w + b.w;
    ((float4*)(CX + (size_t)r * DIM))[c4] = o;
}

// ---------------------------------------------------------------------------
// Tiled f32 GEMM with optional split-K (KS>1: gridDim.z slices, atomicAdd
// into pre-zeroed C; bias applied by slice 0). BM x BN tile, 8x4 micro.
// ---------------------------------------------------------------------------
template <int BM, int BN, bool BT, int KS>
__global__ __launch_bounds__((BM / 8) * (BN / 4)) void gemm_f32(
    const float* __restrict__ A, const float* __restrict__ A2, int asplit, int lda2,
    const float* __restrict__ B, const float* __restrict__ bias,
    float* __restrict__ C, int M, int N, int K, int lda, int ldb, int ldc, float scale)
{
    constexpr int NT = (BM / 8) * (BN / 4);
    constexpr int EA = BM * 16 / NT;
    constexpr int EB = BN * 16 / NT;
    constexpr int TROW = BN / 4;
    __shared__ float As[16][BM + 4];
    __shared__ float Bs[16][BN + 4];
    const int tid = threadIdx.x;
    const int bm = blockIdx.y * BM, bn = blockIdx.x * BN;
    const int tm = (tid / TROW) * 8, tn = (tid % TROW) * 4;
    const int KCH = KS == 1 ? K : (((K + KS - 1) / KS + 15) & ~15);
    const int kbeg = blockIdx.z * KCH;
    const int kend = (kbeg + KCH < K) ? kbeg + KCH : K;
    float acc[8][4] = {};

    for (int k0 = kbeg; k0 < kend; k0 += 16) {
#pragma unroll
        for (int i = 0; i < EA; i++) {       // A tile: BM rows x 16 k
            int flat = tid * EA + i;
            int r = flat >> 4, kc = flat & 15;
            int gk = k0 + kc;
            float v = 0.f;
            if (gk < kend) {
                int gr = bm + r;
                v = (A2 && gk >= asplit) ? A2[(size_t)gr * lda2 + (gk - asplit)]
                                         : A[(size_t)gr * lda + gk];
            }
            As[kc][r] = v;
        }
        if (!BT) {                            // B[k][n] -> Bs[k][n]
#pragma unroll
            for (int i = 0; i < EB; i++) {
                int flat = tid * EB + i;
                int kb = flat / BN, nb = flat % BN;
                int gk = k0 + kb, gn = bn + nb;
                Bs[kb][nb] = (gk < kend && gn < N) ? B[(size_t)gk * ldb + gn] : 0.f;
            }
        } else {                              // B[n][k] -> Bs[k][n]
#pragma unroll
            for (int i = 0; i < EB; i++) {
                int flat = tid * EB + i;
                int n = flat >> 4, kc = flat & 15;
                int gn = bn + n, gk = k0 + kc;
                Bs[kc][n] = (gn < N && gk < kend) ? B[(size_t)gn * ldb + gk] : 0.f;
            }
        }
        __syncthreads();
#pragma unroll
        for (int kk = 0; kk < 16; kk++) {
            float a[8], b[4];
#pragma unroll
            for (int i = 0; i < 8; i++) a[i] = As[kk][tm + i];
#pragma unroll
            for (int j = 0; j < 4; j++) b[j] = Bs[kk][tn + j];
#pragma unroll
            for (int i = 0; i < 8; i++)
#pragma unroll
                for (int j = 0; j < 4; j++) acc[i][j] += a[i] * b[j];
        }
        __syncthreads();
    }
#pragma unroll
    for (int i = 0; i < 8; i++) {
        int gm = bm + tm + i;
#pragma unroll
        for (int j = 0; j < 4; j++) {
            int gn = bn + tn + j;
            if (gn >= N) continue;
            float v = acc[i][j];
            if (KS == 1) {
                if (bias) v += bias[gn];
                C[(size_t)gm * ldc + gn] = v * scale;
            } else {
                if (bias && blockIdx.z == 0) v += bias[gn];
                atomicAdd(&C[(size_t)gm * ldc + gn], v * scale);
            }
        }
    }
}

// ---------------------------------------------------------------------------
// attn_rows_k: 8 half-wave groups gather neighbors with fused score dot;
// wave-parallel softmax; float4 weighted-sum epilogue.
// ---------------------------------------------------------------------------
template <int DEPTH>
__global__ __launch_bounds__(256) void attn_rows_k(
    const float* __restrict__ nr, const float* __restrict__ ne,
    const float* __restrict__ ee, const float* __restrict__ h1,
    const int* __restrict__ nids, const int* __restrict__ eids,
    const float* __restrict__ nts, const float* __restrict__ deg,
    const float* __restrict__ re, const float* __restrict__ ts,
    const float* __restrict__ tw, const float* __restrict__ tb,
    const float* __restrict__ iw1, const float* __restrict__ ib1,
    const float* __restrict__ KQ, float* __restrict__ WFB)
{
    __shared__ float featb[K_NB][FROW];
    __shared__ float kq_s[FROW];
    __shared__ float score[K_NB], attn_l[K_NB];
    __shared__ float dt_s[K_NB], ss_s[K_NB];
    __shared__ int nid_s[K_NB], eid_s[K_NB];

    const int row = blockIdx.x, tid = threadIdx.x;
    const int g = tid >> 5, l = tid & 31;

    if (tid < K_NB) {
        int nid = nids[row * K_NB + tid];
        nid_s[tid] = nid; eid_s[tid] = eids[row * K_NB + tid];
        float tc = (DEPTH == 1) ? ts[row / K_NB] : ts[row];
        dt_s[tid] = tc - nts[row * K_NB + tid];
        float rv = re[row * K_NB + tid];
        ss_s[tid] = (rv == 0.f) ? 0.f : deg[row * K_NB + tid] / rv;
    }
    kq_s[tid] = KQ[(size_t)row * FEAT + tid];
    if (tid < FEAT - 256) kq_s[256 + tid] = KQ[(size_t)row * FEAT + 256 + tid];
    __syncthreads();

    for (int rr = g; rr < K_NB; rr += 8) {
        const int nid = nid_s[rr], eid = eid_s[rr];
        float4 xa;
        if (DEPTH == 1) {
            const float4 a = ((const float4*)(nr + (size_t)nid * DIM))[l];
            const float4 b = ((const float4*)(ne + (size_t)nid * DIM))[l];
            xa.x = a.x + b.x; xa.y = a.y + b.y; xa.z = a.z + b.z; xa.w = a.w + b.w;
        } else {
            xa = ((const float4*)(h1 + ((size_t)row * K_NB + rr) * DIM))[l];
        }
        const float4 xe = ((const float4*)(ee + (size_t)eid * DIM))[l];
        const float dt = dt_s[rr];
        const float4 tw4 = ((const float4*)tw)[l];
        const float4 tb4 = ((const float4*)tb)[l];
        float4 xt;
        xt.x = __cosf(dt * tw4.x + tb4.x);
        xt.y = __cosf(dt * tw4.y + tb4.y);
        xt.z = __cosf(dt * tw4.z + tb4.z);
        xt.w = __cosf(dt * tw4.w + tb4.w);

        ((float4*)&featb[rr][0])[l]   = xa;
        ((float4*)&featb[rr][128])[l] = xe;
        ((float4*)&featb[rr][256])[l] = xt;

        const int c = 4 * l;
        float sc = xa.x * kq_s[c]       + xa.y * kq_s[c + 1]       + xa.z * kq_s[c + 2]       + xa.w * kq_s[c + 3]
                 + xe.x * kq_s[128 + c] + xe.y * kq_s[128 + c + 1] + xe.z * kq_s[128 + c + 2] + xe.w * kq_s[128 + c + 3]
                 + xt.x * kq_s[256 + c] + xt.y * kq_s[256 + c + 1] + xt.z * kq_s[256 + c + 2] + xt.w * kq_s[256 + c + 3];
        if (l < IMP / 4) {
            const float s = ss_s[rr];
            const float4 w1 = ((const float4*)iw1)[l];
            const float4 b1 = ((const float4*)ib1)[l];
            float4 hv;
            hv.x = fmaxf(s * w1.x + b1.x, 0.f);
            hv.y = fmaxf(s * w1.y + b1.y, 0.f);
            hv.z = fmaxf(s * w1.z + b1.z, 0.f);
            hv.w = fmaxf(s * w1.w + b1.w, 0.f);
            ((float4*)&featb[rr][FB])[l] = hv;
            sc += hv.x * kq_s[FB + c] + hv.y * kq_s[FB + c + 1]
                + hv.z * kq_s[FB + c + 2] + hv.w * kq_s[FB + c + 3];
        }
#pragma unroll
        for (int off = 16; off >= 1; off >>= 1) sc += __shfl_down(sc, off, 32);
        if (l == 0) score[rr] = sc;
    }
    __syncthreads();

    if (tid < 32) {
        float sc = (tid < K_NB) ? ((nid_s[tid] == 0) ? -1e9f : score[tid]) : -3.0e38f;
        float mx = sc;
#pragma unroll
        for (int off = 16; off >= 1; off >>= 1) mx = fmaxf(mx, __shfl_xor(mx, off, 32));
        float e = __expf(sc - mx);
        float sum = e;
#pragma unroll
        for (int off = 16; off >= 1; off >>= 1) sum += __shfl_xor(sum, off, 32);
        if (tid < K_NB) attn_l[tid] = e / sum;
    }
    __syncthreads();

    if (tid < FEAT / 4) {
        float4 acc = {0.f, 0.f, 0.f, 0.f};
#pragma unroll 4
        for (int r = 0; r < K_NB; r++) {
            const float a = attn_l[r];
            const float4 f = ((const float4*)&featb[r][0])[tid];
            acc.x += a * f.x; acc.y += a * f.y; acc.z += a * f.z; acc.w += a * f.w;
        }
        ((float4*)(WFB + (size_t)row * FEAT))[tid] = acc;
    }
}

// ---------------------------------------------------------------------------
// gates_out_k: phase 1 = lstm gates (i,g,o) on a 64x64 tile of HN;
// phase 2 = h_tile(64x64) @ WoutB[bn:bn+64, 0:128] accumulated into Hout
// via atomicAdd. Hout must be pre-initialized with CX @ WoutA.
// h tile lives in LDS aliasing the dead As|Bs region (exactly 4352 floats).
// ---------------------------------------------------------------------------
__global__ __launch_bounds__(256) void gates_out_k(
    const float* __restrict__ CTX, const float* __restrict__ wih,
    const float* __restrict__ bias, const float* __restrict__ WoutB,
    float* __restrict__ Hout, int M)
{
    __shared__ float smem[16 * 68 + 3 * 16 * 68];   // As[16][68] | Bs[3][16][68]; h_s alias
    __shared__ float Bs2[16][132];
    float* As  = smem;                 // [16][68]
    float* Bs  = smem + 16 * 68;       // [3][16][68]
    float* h_s = smem;                 // [64][68] (phase 2)

    const int tid = threadIdx.x;
    const int bm = blockIdx.y * 64, bn = blockIdx.x * 64;
    const int tm = (tid >> 4) * 4, tn = (tid & 15) * 4;
    float acc[3][4][4] = {};

    // ---- phase 1: gate GEMM (K = 256) ----
    for (int k0 = 0; k0 < DKQ; k0 += 16) {
        int r = tid >> 2, kc = (tid & 3) * 4;
#pragma unroll
        for (int i = 0; i < 4; i++) As[(kc + i) * 68 + r] = CTX[(size_t)(bm + r) * DKQ + k0 + kc + i];
        int kb = tid >> 4, nb = (tid & 15) * 4;
#pragma unroll
        for (int i = 0; i < 4; i++) {
            Bs[0 * 1088 + kb * 68 + nb + i] = wih[(size_t)(k0 + kb) * 4096 +    0 + bn + nb + i];
            Bs[1 * 1088 + kb * 68 + nb + i] = wih[(size_t)(k0 + kb) * 4096 + 2048 + bn + nb + i];
            Bs[2 * 1088 + kb * 68 + nb + i] = wih[(size_t)(k0 + kb) * 4096 + 3072 + bn + nb + i];
        }
        __syncthreads();
#pragma unroll
        for (int kk = 0; kk < 16; kk++) {
            float a[4], b0[4], b1[4], b2v[4];
#pragma unroll
            for (int i = 0; i < 4; i++) a[i] = As[kk * 68 + tm + i];
#pragma unroll
            for (int j = 0; j < 4; j++) {
                b0[j]  = Bs[0 * 1088 + kk * 68 + tn + j];
                b1[j]  = Bs[1 * 1088 + kk * 68 + tn + j];
                b2v[j] = Bs[2 * 1088 + kk * 68 + tn + j];
            }
#pragma unroll
            for (int i = 0; i < 4; i++)
#pragma unroll
                for (int j = 0; j < 4; j++) {
                    acc[0][i][j] += a[i] * b0[j];
                    acc[1][i][j] += a[i] * b1[j];
                    acc[2][i][j] += a[i] * b2v[j];
                }
        }
        __syncthreads();
    }

    // ---- epilogue: h = sig(o)*tanh(sig(i)*tanh(g)) -> h_s (aliases As|Bs) ----
#pragma unroll
    for (int i = 0; i < 4; i++)
#pragma unroll
        for (int j = 0; j < 4; j++) {
            int n = bn + tn + j;
            float iv = acc[0][i][j] + bias[n];
            float gv = acc[1][i][j] + bias[2048 + n];
            float ov = acc[2][i][j] + bias[3072 + n];
            float c = sigmoidf_(iv) * tanhf(gv);
            h_s[(tm + i) * 68 + tn + j] = sigmoidf_(ov) * tanhf(c);
        }
    __syncthreads();

    // ---- phase 2: h_s(64x64) @ WoutB[bn.., 0:128] -> atomicAdd into Hout ----
    const int tm2 = (tid >> 5) * 8, tn2 = (tid & 31) * 4;
    float acc2[8][4] = {};
    for (int kc0 = 0; kc0 < 64; kc0 += 16) {
#pragma unroll
        for (int i = 0; i < 8; i++) {
            int flat = tid * 8 + i;
            int kb = flat >> 7, nb = flat & 127;
            Bs2[kb][nb] = WoutB[(size_t)(bn + kc0 + kb) * DIM + nb];
        }
        __syncthreads();
#pragma unroll
        for (int kk = 0; kk < 16; kk++) {
            float a[8];
#pragma unroll
            for (int i = 0; i < 8; i++) a[i] = h_s[(tm2 + i) * 68 + kc0 + kk];
            const float4 bf = *(const float4*)&Bs2[kk][tn2];
#pragma unroll
            for (int i = 0; i < 8; i++) {
                acc2[i][0] += a[i] * bf.x; acc2[i][1] += a[i] * bf.y;
                acc2[i][2] += a[i] * bf.z; acc2[i][3] += a[i] * bf.w;
            }
        }
        __syncthreads();
    }
#pragma unroll
    for (int i = 0; i < 8; i++)
#pragma unroll
        for (int j = 0; j < 4; j++)
            atomicAdd(&Hout[(size_t)(bm + tm2 + i) * DIM + tn2 + j], acc2[i][j]);
}

// ---------------------------------------------------------------------------
extern "C" void kernel_launch(void* const* d_in, const int* in_sizes, int n_in,
                              void* d_out, int out_size, void* d_ws, size_t ws_size,
                              hipStream_t stream)
{
    const float* nr   = (const float*)d_in[0];
    const float* ne   = (const float*)d_in[1];
    const float* ee   = (const float*)d_in[2];
    const float* tw   = (const float*)d_in[3];
    const float* tb   = (const float*)d_in[4];
    const float* iw1  = (const float*)d_in[5];
    const float* ib1  = (const float*)d_in[6];
    const float* W2   = (const float*)d_in[7];
    const float* ib2  = (const float*)d_in[8];
    const float* Wq   = (const float*)d_in[9];
    const float* Wk   = (const float*)d_in[10];
    const float* Wv   = (const float*)d_in[11];
    const float* wih  = (const float*)d_in[12];
    /* lstm_whh d_in[13] unused: h0 == 0 */
    const float* lb   = (const float*)d_in[14];
    const float* Wout = (const float*)d_in[15];
    const float* ts     = (const float*)d_in[16];
    const float* n2_ts  = (const float*)d_in[17];
    const float* n1_ts  = (const float*)d_in[18];
    const float* n2_re  = (const float*)d_in[19];
    const float* n2_deg = (const float*)d_in[20];
    const float* n1_re  = (const float*)d_in[21];
    const float* n1_deg = (const float*)d_in[22];
    const int* center_nids = (const int*)d_in[23];
    const int* n2_nids     = (const int*)d_in[24];
    const int* n2_eids     = (const int*)d_in[25];
    const int* n1_nids     = (const int*)d_in[26];
    const int* n1_eids     = (const int*)d_in[27];

    const float* WoutA = Wout;               // rows [0:128)   -> CX part
    const float* WoutB = Wout + 128 * DIM;   // rows [128:1152) -> HN part

    // ---- workspace layout (~31.6 MB peak; no HN buffer needed anymore) ----
    float* ws   = (float*)d_ws;
    float* VW   = ws;                        // 484*256
    float* WK   = VW  + FEAT * DKQ;          // 484*256
    float* qc0  = WK  + FEAT * DKQ;          // 256
    float* cv0  = qc0 + DKQ;                 // 256
    float* WQK  = cv0 + DKQ;                 // 128*484
    float* kc0  = WQK + DIM * FEAT;          // 512
    float* CX   = kc0 + 512;                 // 5120*128
    float* H1   = CX  + NB1 * DIM;           // 5120*128
    float* CTX  = H1  + NB1 * DIM;           // 5120*256
    float* KQ   = CTX + NB1 * DKQ;           // 5120*484
    float* WFB  = KQ  + NB1 * FEAT;          // 5120*484

    precompute_k<<<FB + IMP + 2, 256, 0, stream>>>(tb, ib2, Wq, Wk, Wv, W2, VW, WK, qc0, cv0);
    precompute2_k<<<FEAT, 128, 0, stream>>>(Wq, WK, qc0, WQK, kc0);

    // ================= depth 1 (M = 5120) =================
    {
        const int M = NB1;
        cx_gather_k<<<M / 4, 128, 0, stream>>>(nr, ne, n2_nids, CX, M);
        gemm_f32<64, 64, false, 1><<<dim3(8, M / 64), 128, 0, stream>>>(
            CX, nullptr, 0, 0, WQK, kc0, KQ, M, FEAT, DIM, DIM, FEAT, FEAT, 1.f);
        attn_rows_k<1><<<M, 256, 0, stream>>>(nr, ne, ee, nullptr,
            n1_nids, n1_eids, n1_ts, n1_deg, n1_re, ts, tw, tb, iw1, ib1, KQ, WFB);
        hipMemsetAsync(CTX, 0, (size_t)M * DKQ * sizeof(float), stream);
        gemm_f32<64, 64, false, 4><<<dim3(4, M / 64, 4), 128, 0, stream>>>(
            WFB, nullptr, 0, 0, VW, cv0, CTX, M, DKQ, FEAT, FEAT, DKQ, DKQ, 1.f);
        gemm_f32<64, 32, false, 1><<<dim3(4, M / 64), 64, 0, stream>>>(
            CX, nullptr, 0, 0, WoutA, nullptr, H1, M, DIM, DIM, DIM, DIM, DIM, 1.f);
        gates_out_k<<<dim3(16, M / 64), 256, 0, stream>>>(CTX, wih, lb, WoutB, H1, M);
    }
    // ================= depth 2 (M = 256) =================
    {
        const int M = NB2;
        cx_gather_k<<<M / 4, 128, 0, stream>>>(nr, ne, center_nids, CX, M);
        gemm_f32<64, 64, false, 1><<<dim3(8, M / 64), 128, 0, stream>>>(
            CX, nullptr, 0, 0, WQK, kc0, KQ, M, FEAT, DIM, DIM, FEAT, FEAT, 1.f);
        attn_rows_k<2><<<M, 256, 0, stream>>>(nr, ne, ee, H1,
            n2_nids, n2_eids, n2_ts, n2_deg, n2_re, ts, tw, tb, iw1, ib1, KQ, WFB);
        hipMemsetAsync(CTX, 0, (size_t)M * DKQ * sizeof(float), stream);
        gemm_f32<64, 64, false, 4><<<dim3(4, M / 64, 4), 128, 0, stream>>>(
            WFB, nullptr, 0, 0, VW, cv0, CTX, M, DKQ, FEAT, FEAT, DKQ, DKQ, 1.f);
        gemm_f32<64, 32, false, 1><<<dim3(4, M / 64), 64, 0, stream>>>(
            CX, nullptr, 0, 0, WoutA, nullptr, (float*)d_out, M, DIM, DIM, DIM, DIM, DIM, 1.f);
        gates_out_k<<<dim3(16, M / 64), 256, 0, stream>>>(CTX, wih, lb, WoutB, (float*)d_out, M);
    }
}